// Round 4
// baseline (151.480 us; speedup 1.0000x reference)
//
#include <hip/hip_runtime.h>
#include <hip/hip_bf16.h>
#include <math.h>

#define NB   256
#define KIN  1024
#define ND   512
#define NP   2048
#define NTOT 4096   // Wm rows + proxy rows stacked

typedef __bf16 bf16x8 __attribute__((ext_vector_type(8)));
typedef float  f32x4  __attribute__((ext_vector_type(4)));
typedef unsigned short ush8 __attribute__((ext_vector_type(8)));

// ws byte offsets (16B aligned)
#define OFF_WPB    0u          // 4096*512 bf16 = 4 MB
#define OFF_FEATB  4194304u    // 256*512 bf16  = 256 KB
#define OFF_PN2    4456448u    // 2048 f32
#define OFF_LOGITS 4464640u    // 256*2048 f32  = 2 MB
#define OFF_SYNC   6561792u    // 64 B: bar[4] counters + accum[2] floats

__device__ __forceinline__ float bf2f(unsigned short h) {
    union { unsigned u; float f; } v; v.u = ((unsigned)h) << 16; return v.f;
}

__device__ __forceinline__ ush8 pack8(float4 f0, float4 f1) {
    union { ush8 v; __hip_bfloat162 h[4]; } o;
    o.h[0] = __float22bfloat162_rn(make_float2(f0.x, f0.y));
    o.h[1] = __float22bfloat162_rn(make_float2(f0.z, f0.w));
    o.h[2] = __float22bfloat162_rn(make_float2(f1.x, f1.y));
    o.h[3] = __float22bfloat162_rn(make_float2(f1.z, f1.w));
    return o.v;
}

// async 16B global->LDS DMA (dest = wave-uniform lds base + lane*16)
__device__ __forceinline__ void async16(const unsigned short* g, unsigned short* l) {
    __builtin_amdgcn_global_load_lds(
        (const __attribute__((address_space(1))) unsigned int*)g,
        (__attribute__((address_space(3))) unsigned int*)l, 16, 0, 0);
}

// grid barrier: 256 blocks, all co-resident (1/CU). thread 0 arrives+spins,
// rest wait at __syncthreads. fence-fence sync via __threadfence (agent scope).
__device__ __forceinline__ void gridbar(unsigned* bar, int idx) {
    __syncthreads();
    if (threadIdx.x == 0) {
        __threadfence();   // release prior writes (cross-XCD via L2 wb/inv)
        __hip_atomic_fetch_add(&bar[idx], 1u, __ATOMIC_RELAXED, __HIP_MEMORY_SCOPE_AGENT);
        while (__hip_atomic_load(&bar[idx], __ATOMIC_RELAXED, __HIP_MEMORY_SCOPE_AGENT) < 256u)
            __builtin_amdgcn_s_sleep(2);
        __threadfence();   // acquire
    }
    __syncthreads();
}

__device__ __forceinline__ float block_reduce(float v, float* sred, int op)
{
    const int lane = threadIdx.x & 63, wave = threadIdx.x >> 6;
#pragma unroll
    for (int off = 32; off; off >>= 1) {
        float o = __shfl_down(v, off);
        v = op ? fmaxf(v, o) : (v + o);
    }
    if (lane == 0) sred[wave] = v;
    __syncthreads();
    if (threadIdx.x == 0) {
        float r = sred[0];
#pragma unroll
        for (int wv = 1; wv < 4; ++wv) r = op ? fmaxf(r, sred[wv]) : (r + sred[wv]);
        sred[0] = r;
    }
    __syncthreads();
    float r = sred[0];
    __syncthreads();
    return r;
}

// ---------------------------------------------------------------------------
// Single mega-kernel, grid=256 x 256thr, 3 grid barriers.
// ---------------------------------------------------------------------------
__global__ __launch_bounds__(256) void k_all(
    const float* __restrict__ x, const int* __restrict__ y,
    const float* __restrict__ Wb, const float* __restrict__ bb,
    const float* __restrict__ Wm, const float* __restrict__ bm,
    const float* __restrict__ prox,
    unsigned short* __restrict__ featb, unsigned short* __restrict__ WPb,
    float* __restrict__ pn2, float* __restrict__ logits,
    unsigned* __restrict__ bar, float* __restrict__ accum,
    float* __restrict__ out, float* __restrict__ tail)
{
    __shared__ unsigned short As[2][64 * 32];
    __shared__ unsigned short Bs[2][64 * 32];
    __shared__ float sred[4];
    const int bid = blockIdx.x, t = threadIdx.x;
    const int lane = t & 63, w = t >> 6;

    // ---------------- P0: feat GEMM (blocks 0-31) || casts+pn2 (32-255) ----
    if (bid < 32) {
        const int n0 = (bid & 7) * 64, m0 = (bid >> 3) * 64;
        const int srow = t >> 2, sc = (t & 3) * 8;
        const float* gA = x  + (size_t)(m0 + srow) * KIN + sc;
        const float* gB = Wb + (size_t)(n0 + srow) * KIN + sc;
        float4 a0 = *(const float4*)gA, a1 = *(const float4*)(gA + 4);
        float4 b0 = *(const float4*)gB, b1 = *(const float4*)(gB + 4);
        f32x4 acc[2][2] = {};
        const int wm = (w >> 1) * 32, wn = (w & 1) * 32;
        const int arow = wm + (lane & 15), brow = wn + (lane & 15);
        const int fcol = (lane >> 4) * 8;
        for (int ks = 0; ks < KIN / 32; ++ks) {
            *(ush8*)&As[ks & 1][srow * 32 + sc] = pack8(a0, a1);
            *(ush8*)&Bs[ks & 1][srow * 32 + sc] = pack8(b0, b1);
            __syncthreads();
            if (ks + 1 < KIN / 32) {
                a0 = *(const float4*)(gA + (ks + 1) * 32);
                a1 = *(const float4*)(gA + (ks + 1) * 32 + 4);
                b0 = *(const float4*)(gB + (ks + 1) * 32);
                b1 = *(const float4*)(gB + (ks + 1) * 32 + 4);
            }
            const unsigned short* as = &As[ks & 1][0];
            const unsigned short* bs = &Bs[ks & 1][0];
            bf16x8 af0 = *(const bf16x8*)&as[(arow     ) * 32 + fcol];
            bf16x8 af1 = *(const bf16x8*)&as[(arow + 16) * 32 + fcol];
            bf16x8 bf0 = *(const bf16x8*)&bs[(brow     ) * 32 + fcol];
            bf16x8 bf1 = *(const bf16x8*)&bs[(brow + 16) * 32 + fcol];
            acc[0][0] = __builtin_amdgcn_mfma_f32_16x16x32_bf16(af0, bf0, acc[0][0], 0, 0, 0);
            acc[0][1] = __builtin_amdgcn_mfma_f32_16x16x32_bf16(af0, bf1, acc[0][1], 0, 0, 0);
            acc[1][0] = __builtin_amdgcn_mfma_f32_16x16x32_bf16(af1, bf0, acc[1][0], 0, 0, 0);
            acc[1][1] = __builtin_amdgcn_mfma_f32_16x16x32_bf16(af1, bf1, acc[1][1], 0, 0, 0);
            __syncthreads();
        }
        const int q = lane >> 4, cn = lane & 15;
#pragma unroll
        for (int i = 0; i < 2; ++i)
#pragma unroll
            for (int j = 0; j < 2; ++j) {
                const int n = n0 + wn + 16 * j + cn;
                const float bias = bb[n];
#pragma unroll
                for (int r = 0; r < 4; ++r) {
                    const int m = m0 + wm + 16 * i + q * 4 + r;
                    featb[m * ND + n] = __hip_bfloat16_raw(__hip_bfloat16(acc[i][j][r] + bias)).x;
                }
            }
    } else {
        // 224 blocks x 4 waves = 896 waves over 4096 rows
        const int gw = (bid - 32) * 4 + w;
        for (int r = gw; r < NTOT; r += 896) {
            const float* src = (r < NP) ? (Wm + (size_t)r * ND) : (prox + (size_t)(r - NP) * ND);
            float4 v0 = *(const float4*)(src + lane * 8);
            float4 v1 = *(const float4*)(src + lane * 8 + 4);
            *(ush8*)(WPb + (size_t)r * ND + lane * 8) = pack8(v0, v1);
            if (r >= NP) {
                float s = v0.x*v0.x + v0.y*v0.y + v0.z*v0.z + v0.w*v0.w
                        + v1.x*v1.x + v1.y*v1.y + v1.z*v1.z + v1.w*v1.w;
#pragma unroll
                for (int off = 32; off; off >>= 1) s += __shfl_down(s, off);
                if (lane == 0) pn2[r - NP] = s;
            }
        }
    }
    gridbar(bar, 0);

    // ---------------- P1: head GEMM, 64x64 tile, 256 blocks ---------------
    {
        const int n0 = (bid & 63) * 64;   // 64 n-tiles over 4096
        const int m0 = (bid >> 6) * 64;   // 4 m-tiles over 256
        const int drow = w * 16 + (lane >> 2), dcol = (lane & 3) * 8;
        const unsigned short* gA = featb + (size_t)(m0 + drow) * ND + dcol;
        const unsigned short* gB = WPb   + (size_t)(n0 + drow) * ND + dcol;
#define ISSUE(buf, ks)                                        \
        do {                                                  \
            async16(gA + (ks) * 32, &As[buf][(w * 16) * 32]); \
            async16(gB + (ks) * 32, &Bs[buf][(w * 16) * 32]); \
        } while (0)
        f32x4 acc[2][2] = {};
        const int wm = (w >> 1) * 32, wn = (w & 1) * 32;
        const int fr = lane & 15, fcol = (lane >> 4) * 8;
        ISSUE(0, 0);
        for (int ks = 0; ks < ND / 32; ++ks) {
            __syncthreads();
            if (ks + 1 < ND / 32) ISSUE((ks + 1) & 1, ks + 1);
            const unsigned short* as = &As[ks & 1][0];
            const unsigned short* bs = &Bs[ks & 1][0];
            bf16x8 af0 = *(const bf16x8*)&as[(wm      + fr) * 32 + fcol];
            bf16x8 af1 = *(const bf16x8*)&as[(wm + 16 + fr) * 32 + fcol];
            bf16x8 bf0 = *(const bf16x8*)&bs[(wn      + fr) * 32 + fcol];
            bf16x8 bf1 = *(const bf16x8*)&bs[(wn + 16 + fr) * 32 + fcol];
            acc[0][0] = __builtin_amdgcn_mfma_f32_16x16x32_bf16(af0, bf0, acc[0][0], 0, 0, 0);
            acc[0][1] = __builtin_amdgcn_mfma_f32_16x16x32_bf16(af0, bf1, acc[0][1], 0, 0, 0);
            acc[1][0] = __builtin_amdgcn_mfma_f32_16x16x32_bf16(af1, bf0, acc[1][0], 0, 0, 0);
            acc[1][1] = __builtin_amdgcn_mfma_f32_16x16x32_bf16(af1, bf1, acc[1][1], 0, 0, 0);
            __syncthreads();
        }
#undef ISSUE
        const bool isProxy = (n0 >= NP);
        const int q = lane >> 4;
#pragma unroll
        for (int i = 0; i < 2; ++i)
#pragma unroll
            for (int j = 0; j < 2; ++j) {
                const int n = n0 + wn + 16 * j + fr;
                const float cadd = isProxy ? pn2[n - NP] : bm[n];
#pragma unroll
                for (int r = 0; r < 4; ++r) {
                    const int m = m0 + wm + 16 * i + q * 4 + r;
                    const float v = acc[i][j][r];
                    if (isProxy) logits[m * NP + (n - NP)] = 2.0f * v - cadd;
                    else         out[m * NP + n] = v + cadd;
                }
            }
    }
    gridbar(bar, 1);

    // ---------------- P2: per-row softmax-CE + feat norm ------------------
    {
        const int b = bid;
        float s = 0.f;
#pragma unroll
        for (int c = 0; c < 2; ++c) {
            float v = bf2f(featb[b * ND + t * 2 + c]); s += v * v;
        }
        float fn2 = block_reduce(s, sred, 0);

        const float* lr = logits + (size_t)b * NP;
        float lv[8], mx = -INFINITY;
#pragma unroll
        for (int j = 0; j < 8; ++j) { lv[j] = lr[t + 256 * j]; mx = fmaxf(mx, lv[j]); }
        float MX = block_reduce(mx, sred, 1);
        float es = 0.f;
#pragma unroll
        for (int j = 0; j < 8; ++j) es += __expf(lv[j] - MX);
        float SUM = block_reduce(es, sred, 0);

        if (t == 0) {
            float ly = lr[y[b]];
            atomicAdd(&accum[0], ly - MX - __logf(SUM));
            atomicAdd(&accum[1], sqrtf(fn2));
        }
    }
    gridbar(bar, 2);

    // ---------------- P3: tail --------------------------------------------
    if (bid == 0 && t == 0) {
        float s0 = __hip_atomic_load(&accum[0], __ATOMIC_RELAXED, __HIP_MEMORY_SCOPE_AGENT);
        float s1 = __hip_atomic_load(&accum[1], __ATOMIC_RELAXED, __HIP_MEMORY_SCOPE_AGENT);
        tail[0] = -s0 / (float)NB;
        tail[1] =  s1 / (float)NB;
    }
}

extern "C" void kernel_launch(void* const* d_in, const int* in_sizes, int n_in,
                              void* d_out, int out_size, void* d_ws, size_t ws_size,
                              hipStream_t stream)
{
    const float* x       = (const float*)d_in[0];
    const int*   y       = (const int*)  d_in[1];
    const float* Wb      = (const float*)d_in[2];
    const float* bb      = (const float*)d_in[3];
    const float* Wm      = (const float*)d_in[4];
    const float* bm      = (const float*)d_in[5];
    const float* proxies = (const float*)d_in[6];

    char* ws = (char*)d_ws;
    unsigned short* WPb    = (unsigned short*)(ws + OFF_WPB);
    unsigned short* featb  = (unsigned short*)(ws + OFF_FEATB);
    float*          pn2    = (float*)(ws + OFF_PN2);
    float*          logits = (float*)(ws + OFF_LOGITS);
    unsigned*       bar    = (unsigned*)(ws + OFF_SYNC);        // bar[4]
    float*          accum  = (float*)(ws + OFF_SYNC + 16);      // accum[2]

    float* out  = (float*)d_out;
    float* tail = out + (size_t)NB * NP;

    hipMemsetAsync(ws + OFF_SYNC, 0, 64, stream);
    k_all<<<dim3(256), dim3(256), 0, stream>>>(
        x, y, Wb, bb, Wm, bm, proxies,
        featb, WPb, pn2, logits, bar, accum, out, tail);
}

// Round 5
// 111.590 us; speedup vs baseline: 1.3575x; 1.3575x over previous
//
#include <hip/hip_runtime.h>
#include <hip/hip_bf16.h>
#include <math.h>

#define NB   256
#define KIN  1024
#define ND   512
#define NP   2048
#define NTOT 4096   // Wm rows + proxy rows stacked

typedef __bf16 bf16x8 __attribute__((ext_vector_type(8)));
typedef float  f32x4  __attribute__((ext_vector_type(4)));
typedef unsigned short ush8 __attribute__((ext_vector_type(8)));

// ws byte offsets (16B aligned)
#define OFF_WPB    0u          // 4096*512 bf16 = 4 MB
#define OFF_FEATB  4194304u    // 256*512 bf16  = 256 KB
#define OFF_PN2    4456448u    // 2048 f32
#define OFF_LOGITS 4464640u    // 256*2048 f32  = 2 MB
#define OFF_SYNC   6561792u    // 64 B: ticket + accum[2]

__device__ __forceinline__ float bf2f(unsigned short h) {
    union { unsigned u; float f; } v; v.u = ((unsigned)h) << 16; return v.f;
}

__device__ __forceinline__ ush8 pack8(float4 f0, float4 f1) {
    union { ush8 v; __hip_bfloat162 h[4]; } o;
    o.h[0] = __float22bfloat162_rn(make_float2(f0.x, f0.y));
    o.h[1] = __float22bfloat162_rn(make_float2(f0.z, f0.w));
    o.h[2] = __float22bfloat162_rn(make_float2(f1.x, f1.y));
    o.h[3] = __float22bfloat162_rn(make_float2(f1.z, f1.w));
    return o.v;
}

// async 16B global->LDS DMA (lds dest = wave-uniform base + lane*16)
__device__ __forceinline__ void async16(const unsigned short* g, unsigned short* l) {
    __builtin_amdgcn_global_load_lds(
        (const __attribute__((address_space(1))) unsigned int*)g,
        (__attribute__((address_space(3))) unsigned int*)l, 16, 0, 0);
}

// ---------------------------------------------------------------------------
// K1: blocks [0,32)    : feat GEMM 64x64 (inline fp32->bf16, dbuf pipeline)
//     blocks [32,160)  : cast x -> (unused dst? no: x feeds GEMM directly) --
//                        actually: [32,160) cast nothing; see mapping below.
//     [32,1440): cast Wm+prox -> WPb (+pn2); block 32 also zeros sync area.
// ---------------------------------------------------------------------------
__global__ __launch_bounds__(256) void k_one(
    const float* __restrict__ x, const float* __restrict__ Wb,
    const float* __restrict__ bb, const float* __restrict__ Wm,
    const float* __restrict__ prox,
    unsigned short* __restrict__ featb, unsigned short* __restrict__ WPb,
    float* __restrict__ pn2, unsigned* __restrict__ sync_area)
{
    const int bid = blockIdx.x, t = threadIdx.x;
    const int lane = t & 63, w = t >> 6;
    if (bid < 32) {
        // ---- feat GEMM: featb = bf16(x @ Wb.T + bb), 64x64 tile, K=1024 ----
        __shared__ unsigned short As[2][64 * 32];
        __shared__ unsigned short Bs[2][64 * 32];
        const int n0 = (bid & 7) * 64, m0 = (bid >> 3) * 64;
        const int srow = t >> 2, sc = (t & 3) * 8;
        const float* gA = x  + (size_t)(m0 + srow) * KIN + sc;
        const float* gB = Wb + (size_t)(n0 + srow) * KIN + sc;
        float4 a0 = *(const float4*)gA, a1 = *(const float4*)(gA + 4);
        float4 b0 = *(const float4*)gB, b1 = *(const float4*)(gB + 4);
        f32x4 acc[2][2] = {};
        const int wm = (w >> 1) * 32, wn = (w & 1) * 32;
        const int arow = wm + (lane & 15), brow = wn + (lane & 15);
        const int fcol = (lane >> 4) * 8;
        for (int ks = 0; ks < KIN / 32; ++ks) {
            *(ush8*)&As[ks & 1][srow * 32 + sc] = pack8(a0, a1);
            *(ush8*)&Bs[ks & 1][srow * 32 + sc] = pack8(b0, b1);
            __syncthreads();
            if (ks + 1 < KIN / 32) {        // prefetch flies under MFMAs
                a0 = *(const float4*)(gA + (ks + 1) * 32);
                a1 = *(const float4*)(gA + (ks + 1) * 32 + 4);
                b0 = *(const float4*)(gB + (ks + 1) * 32);
                b1 = *(const float4*)(gB + (ks + 1) * 32 + 4);
            }
            const unsigned short* as = &As[ks & 1][0];
            const unsigned short* bs = &Bs[ks & 1][0];
            bf16x8 af0 = *(const bf16x8*)&as[(arow     ) * 32 + fcol];
            bf16x8 af1 = *(const bf16x8*)&as[(arow + 16) * 32 + fcol];
            bf16x8 bf0 = *(const bf16x8*)&bs[(brow     ) * 32 + fcol];
            bf16x8 bf1 = *(const bf16x8*)&bs[(brow + 16) * 32 + fcol];
            acc[0][0] = __builtin_amdgcn_mfma_f32_16x16x32_bf16(af0, bf0, acc[0][0], 0, 0, 0);
            acc[0][1] = __builtin_amdgcn_mfma_f32_16x16x32_bf16(af0, bf1, acc[0][1], 0, 0, 0);
            acc[1][0] = __builtin_amdgcn_mfma_f32_16x16x32_bf16(af1, bf0, acc[1][0], 0, 0, 0);
            acc[1][1] = __builtin_amdgcn_mfma_f32_16x16x32_bf16(af1, bf1, acc[1][1], 0, 0, 0);
        }
        const int q = lane >> 4, cn = lane & 15;
#pragma unroll
        for (int i = 0; i < 2; ++i)
#pragma unroll
            for (int j = 0; j < 2; ++j) {
                const int n = n0 + wn + 16 * j + cn;
                const float bias = bb[n];
#pragma unroll
                for (int r = 0; r < 4; ++r) {
                    const int m = m0 + wm + 16 * i + q * 4 + r;
                    featb[m * ND + n] = __hip_bfloat16_raw(__hip_bfloat16(acc[i][j][r] + bias)).x;
                }
            }
    } else {
        // ---- cast Wm+prox rows (bf16) + pn2; 1408 blocks x 4 waves --------
        if (bid == 32 && t == 0) {
            sync_area[0] = 0u;                       // ticket
            ((float*)sync_area)[4] = 0.f;            // accum[0]
            ((float*)sync_area)[5] = 0.f;            // accum[1]
        }
        const int r = (bid - 32) * 4 + w;            // wave w: one row of 512
        if (r < NTOT) {
            const float* src = (r < NP) ? (Wm + (size_t)r * ND)
                                        : (prox + (size_t)(r - NP) * ND);
            float4 v0 = *(const float4*)(src + lane * 8);
            float4 v1 = *(const float4*)(src + lane * 8 + 4);
            *(ush8*)(WPb + (size_t)r * ND + lane * 8) = pack8(v0, v1);
            if (r >= NP) {
                float s = v0.x*v0.x + v0.y*v0.y + v0.z*v0.z + v0.w*v0.w
                        + v1.x*v1.x + v1.y*v1.y + v1.z*v1.z + v1.w*v1.w;
#pragma unroll
                for (int off = 32; off; off >>= 1) s += __shfl_down(s, off);
                if (lane == 0) pn2[r - NP] = s;
            }
        }
    }
}

// ---------------------------------------------------------------------------
// K2: head GEMM, 64x64 tile x 256 blocks, DMA dbuf, one barrier per k-step.
//  n<2048: out = feat@Wm.T + bm ; n>=2048: logits = 2*feat@prox.T - pn2
// ---------------------------------------------------------------------------
__global__ __launch_bounds__(256) void k_head(
    const unsigned short* __restrict__ featb, const unsigned short* __restrict__ WPb,
    const float* __restrict__ bm, const float* __restrict__ pn2,
    float* __restrict__ out, float* __restrict__ logits)
{
    __shared__ unsigned short As[2][64 * 32];
    __shared__ unsigned short Bs[2][64 * 32];
    const int t = threadIdx.x, lane = t & 63, w = t >> 6;
    const int n0 = blockIdx.x * 64;   // 64 n-tiles over 4096
    const int m0 = blockIdx.y * 64;   // 4 m-tiles over 256
    const int drow = w * 16 + (lane >> 2), dcol = (lane & 3) * 8;
    const unsigned short* gA = featb + (size_t)(m0 + drow) * ND + dcol;
    const unsigned short* gB = WPb   + (size_t)(n0 + drow) * ND + dcol;
#define ISSUE(buf, ks)                                        \
    do {                                                      \
        async16(gA + (ks) * 32, &As[buf][(w * 16) * 32]);     \
        async16(gB + (ks) * 32, &Bs[buf][(w * 16) * 32]);     \
    } while (0)
    f32x4 acc[2][2] = {};
    const int wm = (w >> 1) * 32, wn = (w & 1) * 32;
    const int fr = lane & 15, fcol = (lane >> 4) * 8;
    ISSUE(0, 0);
    for (int ks = 0; ks < ND / 32; ++ks) {
        __syncthreads();                    // drains DMA(ks); prev-buf reads done
        if (ks + 1 < ND / 32) ISSUE((ks + 1) & 1, ks + 1);
        const unsigned short* as = &As[ks & 1][0];
        const unsigned short* bs = &Bs[ks & 1][0];
        bf16x8 af0 = *(const bf16x8*)&as[(wm      + fr) * 32 + fcol];
        bf16x8 af1 = *(const bf16x8*)&as[(wm + 16 + fr) * 32 + fcol];
        bf16x8 bf0 = *(const bf16x8*)&bs[(wn      + fr) * 32 + fcol];
        bf16x8 bf1 = *(const bf16x8*)&bs[(wn + 16 + fr) * 32 + fcol];
        acc[0][0] = __builtin_amdgcn_mfma_f32_16x16x32_bf16(af0, bf0, acc[0][0], 0, 0, 0);
        acc[0][1] = __builtin_amdgcn_mfma_f32_16x16x32_bf16(af0, bf1, acc[0][1], 0, 0, 0);
        acc[1][0] = __builtin_amdgcn_mfma_f32_16x16x32_bf16(af1, bf0, acc[1][0], 0, 0, 0);
        acc[1][1] = __builtin_amdgcn_mfma_f32_16x16x32_bf16(af1, bf1, acc[1][1], 0, 0, 0);
    }
#undef ISSUE
    const bool isProxy = (n0 >= NP);
    const int q = lane >> 4;
#pragma unroll
    for (int i = 0; i < 2; ++i)
#pragma unroll
        for (int j = 0; j < 2; ++j) {
            const int n = n0 + wn + 16 * j + fr;
            const float cadd = isProxy ? pn2[n - NP] : bm[n];
#pragma unroll
            for (int r = 0; r < 4; ++r) {
                const int m = m0 + wm + 16 * i + q * 4 + r;
                const float v = acc[i][j][r];
                if (isProxy) logits[m * NP + (n - NP)] = 2.0f * v - cadd;
                else         out[m * NP + n] = v + cadd;
            }
        }
}

__device__ __forceinline__ float block_reduce(float v, float* sred, int op)
{
    const int lane = threadIdx.x & 63, wave = threadIdx.x >> 6;
#pragma unroll
    for (int off = 32; off; off >>= 1) {
        float o = __shfl_down(v, off);
        v = op ? fmaxf(v, o) : (v + o);
    }
    if (lane == 0) sred[wave] = v;
    __syncthreads();
    if (threadIdx.x == 0) {
        float r = sred[0];
#pragma unroll
        for (int wv = 1; wv < 4; ++wv) r = op ? fmaxf(r, sred[wv]) : (r + sred[wv]);
        sred[0] = r;
    }
    __syncthreads();
    float r = sred[0];
    __syncthreads();
    return r;
}

// K3: per-row logsumexp + gather + feat norm; last-arriving block writes tail.
__global__ __launch_bounds__(256) void k_loss(
    const unsigned short* __restrict__ featb, const float* __restrict__ logits,
    const int* __restrict__ y, unsigned* __restrict__ sync_area,
    float* __restrict__ tail)
{
    __shared__ float sred[4];
    const int b = blockIdx.x, t = threadIdx.x;

    float s = 0.f;
#pragma unroll
    for (int c = 0; c < 2; ++c) {
        float v = bf2f(featb[b * ND + t * 2 + c]); s += v * v;
    }
    float fn2 = block_reduce(s, sred, 0);

    const float* lr = logits + (size_t)b * NP;
    float lv[8], mx = -INFINITY;
#pragma unroll
    for (int j = 0; j < 8; ++j) { lv[j] = lr[t + 256 * j]; mx = fmaxf(mx, lv[j]); }
    float MX = block_reduce(mx, sred, 1);
    float es = 0.f;
#pragma unroll
    for (int j = 0; j < 8; ++j) es += __expf(lv[j] - MX);
    float SUM = block_reduce(es, sred, 0);

    if (t == 0) {
        float* accum = (float*)sync_area + 4;
        atomicAdd(&accum[0], lr[y[b]] - MX - __logf(SUM));
        atomicAdd(&accum[1], sqrtf(fn2));
        unsigned old = __hip_atomic_fetch_add(&sync_area[0], 1u,
                           __ATOMIC_ACQ_REL, __HIP_MEMORY_SCOPE_AGENT);
        if (old == NB - 1) {   // last block: all adds are at coherence point
            float s0 = __hip_atomic_load(&accum[0], __ATOMIC_RELAXED, __HIP_MEMORY_SCOPE_AGENT);
            float s1 = __hip_atomic_load(&accum[1], __ATOMIC_RELAXED, __HIP_MEMORY_SCOPE_AGENT);
            tail[0] = -s0 / (float)NB;
            tail[1] =  s1 / (float)NB;
        }
    }
}

extern "C" void kernel_launch(void* const* d_in, const int* in_sizes, int n_in,
                              void* d_out, int out_size, void* d_ws, size_t ws_size,
                              hipStream_t stream)
{
    const float* x       = (const float*)d_in[0];
    const int*   y       = (const int*)  d_in[1];
    const float* Wb      = (const float*)d_in[2];
    const float* bb      = (const float*)d_in[3];
    const float* Wm      = (const float*)d_in[4];
    const float* bm      = (const float*)d_in[5];
    const float* proxies = (const float*)d_in[6];

    char* ws = (char*)d_ws;
    unsigned short* WPb    = (unsigned short*)(ws + OFF_WPB);
    unsigned short* featb  = (unsigned short*)(ws + OFF_FEATB);
    float*          pn2    = (float*)(ws + OFF_PN2);
    float*          logits = (float*)(ws + OFF_LOGITS);
    unsigned*       sync_a = (unsigned*)(ws + OFF_SYNC);

    float* out  = (float*)d_out;
    float* tail = out + (size_t)NB * NP;

    k_one <<<dim3(1440), dim3(256), 0, stream>>>(
        x, Wb, bb, Wm, proxies, featb, WPb, pn2, sync_a);
    k_head<<<dim3(NTOT / 64, NB / 64), dim3(256), 0, stream>>>(
        featb, WPb, bm, pn2, out, logits);
    k_loss<<<dim3(NB), dim3(256), 0, stream>>>(featb, logits, y, sync_a, tail);
}

// Round 6
// 107.655 us; speedup vs baseline: 1.4071x; 1.0365x over previous
//
#include <hip/hip_runtime.h>
#include <hip/hip_bf16.h>
#include <math.h>

#define NB   256
#define KIN  1024
#define ND   512
#define NP   2048
#define NTOT 4096   // Wm rows + proxy rows stacked

typedef __bf16 bf16x8 __attribute__((ext_vector_type(8)));
typedef float  f32x4  __attribute__((ext_vector_type(4)));
typedef unsigned short ush8 __attribute__((ext_vector_type(8)));

// ws byte offsets (16B aligned)
#define OFF_WPB    0u          // 4096*512 bf16 = 4 MB
#define OFF_FEATB  4194304u    // 256*512 bf16  = 256 KB
#define OFF_PN2    4456448u    // 2048 f32
#define OFF_LOGITS 4464640u    // 256*2048 f32  = 2 MB
#define OFF_ROWLP  6561792u    // 256 f32
#define OFF_ROWNM  6562816u    // 256 f32

__device__ __forceinline__ float bf2f(unsigned short h) {
    union { unsigned u; float f; } v; v.u = ((unsigned)h) << 16; return v.f;
}

__device__ __forceinline__ ush8 pack8(float4 f0, float4 f1) {
    union { ush8 v; __hip_bfloat162 h[4]; } o;
    o.h[0] = __float22bfloat162_rn(make_float2(f0.x, f0.y));
    o.h[1] = __float22bfloat162_rn(make_float2(f0.z, f0.w));
    o.h[2] = __float22bfloat162_rn(make_float2(f1.x, f1.y));
    o.h[3] = __float22bfloat162_rn(make_float2(f1.z, f1.w));
    return o.v;
}

// ---------------------------------------------------------------------------
// K0: cast Wm+prox -> WPb (bf16) + pn2 fused on the same loads.
// 1024 blocks x 4 waves; wave w of block b owns row b*4+w (512 elems).
// ---------------------------------------------------------------------------
__global__ __launch_bounds__(256) void k_prep(
    const float* __restrict__ Wm, const float* __restrict__ prox,
    unsigned short* __restrict__ WPb, float* __restrict__ pn2)
{
    const int t = threadIdx.x, lane = t & 63, w = t >> 6;
    const int r = blockIdx.x * 4 + w;      // 0..4095
    const float* src = (r < NP) ? (Wm + (size_t)r * ND)
                                : (prox + (size_t)(r - NP) * ND);
    float4 v0 = *(const float4*)(src + lane * 8);
    float4 v1 = *(const float4*)(src + lane * 8 + 4);
    *(ush8*)(WPb + (size_t)r * ND + lane * 8) = pack8(v0, v1);
    if (r >= NP) {
        float s = v0.x*v0.x + v0.y*v0.y + v0.z*v0.z + v0.w*v0.w
                + v1.x*v1.x + v1.y*v1.y + v1.z*v1.z + v1.w*v1.w;
#pragma unroll
        for (int off = 32; off; off >>= 1) s += __shfl_down(s, off);
        if (lane == 0) pn2[r - NP] = s;
    }
}

// ---------------------------------------------------------------------------
// K1: feat GEMM: featb = bf16(x @ Wb.T + bb). 64x64 tile, K=1024,
// fp32 inputs with inline packed cvt, dbuf LDS, register prefetch, 1 sync/step.
// ---------------------------------------------------------------------------
__global__ __launch_bounds__(256) void k_feat(
    const float* __restrict__ x, const float* __restrict__ Wb,
    const float* __restrict__ bb, unsigned short* __restrict__ featb)
{
    __shared__ unsigned short As[2][64 * 32];
    __shared__ unsigned short Bs[2][64 * 32];
    const int t = threadIdx.x, lane = t & 63, w = t >> 6;
    const int n0 = blockIdx.x * 64, m0 = blockIdx.y * 64;
    const int srow = t >> 2, sc = (t & 3) * 8;
    const float* gA = x  + (size_t)(m0 + srow) * KIN + sc;
    const float* gB = Wb + (size_t)(n0 + srow) * KIN + sc;
    float4 a0 = *(const float4*)gA, a1 = *(const float4*)(gA + 4);
    float4 b0 = *(const float4*)gB, b1 = *(const float4*)(gB + 4);
    f32x4 acc[2][2] = {};
    const int wm = (w >> 1) * 32, wn = (w & 1) * 32;
    const int arow = wm + (lane & 15), brow = wn + (lane & 15);
    const int fcol = (lane >> 4) * 8;
    for (int ks = 0; ks < KIN / 32; ++ks) {
        *(ush8*)&As[ks & 1][srow * 32 + sc] = pack8(a0, a1);
        *(ush8*)&Bs[ks & 1][srow * 32 + sc] = pack8(b0, b1);
        __syncthreads();
        if (ks + 1 < KIN / 32) {          // prefetch flies under MFMAs
            a0 = *(const float4*)(gA + (ks + 1) * 32);
            a1 = *(const float4*)(gA + (ks + 1) * 32 + 4);
            b0 = *(const float4*)(gB + (ks + 1) * 32);
            b1 = *(const float4*)(gB + (ks + 1) * 32 + 4);
        }
        const unsigned short* as = &As[ks & 1][0];
        const unsigned short* bs = &Bs[ks & 1][0];
        bf16x8 af0 = *(const bf16x8*)&as[(arow     ) * 32 + fcol];
        bf16x8 af1 = *(const bf16x8*)&as[(arow + 16) * 32 + fcol];
        bf16x8 bf0 = *(const bf16x8*)&bs[(brow     ) * 32 + fcol];
        bf16x8 bf1 = *(const bf16x8*)&bs[(brow + 16) * 32 + fcol];
        acc[0][0] = __builtin_amdgcn_mfma_f32_16x16x32_bf16(af0, bf0, acc[0][0], 0, 0, 0);
        acc[0][1] = __builtin_amdgcn_mfma_f32_16x16x32_bf16(af0, bf1, acc[0][1], 0, 0, 0);
        acc[1][0] = __builtin_amdgcn_mfma_f32_16x16x32_bf16(af1, bf0, acc[1][0], 0, 0, 0);
        acc[1][1] = __builtin_amdgcn_mfma_f32_16x16x32_bf16(af1, bf1, acc[1][1], 0, 0, 0);
    }
    const int q = lane >> 4, cn = lane & 15;
#pragma unroll
    for (int i = 0; i < 2; ++i)
#pragma unroll
        for (int j = 0; j < 2; ++j) {
            const int n = n0 + wn + 16 * j + cn;
            const float bias = bb[n];
#pragma unroll
            for (int r = 0; r < 4; ++r) {
                const int m = m0 + wm + 16 * i + q * 4 + r;
                featb[m * ND + n] = __hip_bfloat16_raw(__hip_bfloat16(acc[i][j][r] + bias)).x;
            }
        }
}

// ---------------------------------------------------------------------------
// K2: head GEMM, 64x64 tile x 256 blocks, register-staged (R2-proven) +
// dbuf + register prefetch, 1 sync/step.
//  n<2048: out = feat@Wm.T + bm ; n>=2048: logits = 2*feat@prox.T - pn2
// ---------------------------------------------------------------------------
__global__ __launch_bounds__(256) void k_head(
    const unsigned short* __restrict__ featb, const unsigned short* __restrict__ WPb,
    const float* __restrict__ bm, const float* __restrict__ pn2,
    float* __restrict__ out, float* __restrict__ logits)
{
    __shared__ unsigned short As[2][64 * 32];
    __shared__ unsigned short Bs[2][64 * 32];
    const int t = threadIdx.x, lane = t & 63, w = t >> 6;
    const int n0 = blockIdx.x * 64;   // 64 n-tiles over 4096
    const int m0 = blockIdx.y * 64;   // 4 m-tiles over 256
    const int srow = t >> 2, sc = (t & 3) * 8;
    const unsigned short* gA = featb + (size_t)(m0 + srow) * ND + sc;
    const unsigned short* gB = WPb   + (size_t)(n0 + srow) * ND + sc;
    ush8 va = *(const ush8*)gA, vb = *(const ush8*)gB;
    f32x4 acc[2][2] = {};
    const int wm = (w >> 1) * 32, wn = (w & 1) * 32;
    const int fr = lane & 15, fcol = (lane >> 4) * 8;
    for (int ks = 0; ks < ND / 32; ++ks) {
        *(ush8*)&As[ks & 1][srow * 32 + sc] = va;
        *(ush8*)&Bs[ks & 1][srow * 32 + sc] = vb;
        __syncthreads();
        if (ks + 1 < ND / 32) {
            va = *(const ush8*)(gA + (ks + 1) * 32);
            vb = *(const ush8*)(gB + (ks + 1) * 32);
        }
        const unsigned short* as = &As[ks & 1][0];
        const unsigned short* bs = &Bs[ks & 1][0];
        bf16x8 af0 = *(const bf16x8*)&as[(wm      + fr) * 32 + fcol];
        bf16x8 af1 = *(const bf16x8*)&as[(wm + 16 + fr) * 32 + fcol];
        bf16x8 bf0 = *(const bf16x8*)&bs[(wn      + fr) * 32 + fcol];
        bf16x8 bf1 = *(const bf16x8*)&bs[(wn + 16 + fr) * 32 + fcol];
        acc[0][0] = __builtin_amdgcn_mfma_f32_16x16x32_bf16(af0, bf0, acc[0][0], 0, 0, 0);
        acc[0][1] = __builtin_amdgcn_mfma_f32_16x16x32_bf16(af0, bf1, acc[0][1], 0, 0, 0);
        acc[1][0] = __builtin_amdgcn_mfma_f32_16x16x32_bf16(af1, bf0, acc[1][0], 0, 0, 0);
        acc[1][1] = __builtin_amdgcn_mfma_f32_16x16x32_bf16(af1, bf1, acc[1][1], 0, 0, 0);
    }
    const bool isProxy = (n0 >= NP);
    const int q = lane >> 4;
#pragma unroll
    for (int i = 0; i < 2; ++i)
#pragma unroll
        for (int j = 0; j < 2; ++j) {
            const int n = n0 + wn + 16 * j + fr;
            const float cadd = isProxy ? pn2[n - NP] : bm[n];
#pragma unroll
            for (int r = 0; r < 4; ++r) {
                const int m = m0 + wm + 16 * i + q * 4 + r;
                const float v = acc[i][j][r];
                if (isProxy) logits[m * NP + (n - NP)] = 2.0f * v - cadd;
                else         out[m * NP + n] = v + cadd;
            }
        }
}

__device__ __forceinline__ float block_reduce(float v, float* sred, int op)
{
    const int lane = threadIdx.x & 63, wave = threadIdx.x >> 6;
#pragma unroll
    for (int off = 32; off; off >>= 1) {
        float o = __shfl_down(v, off);
        v = op ? fmaxf(v, o) : (v + o);
    }
    if (lane == 0) sred[wave] = v;
    __syncthreads();
    if (threadIdx.x == 0) {
        float r = sred[0];
#pragma unroll
        for (int wv = 1; wv < 4; ++wv) r = op ? fmaxf(r, sred[wv]) : (r + sred[wv]);
        sred[0] = r;
    }
    __syncthreads();
    float r = sred[0];
    __syncthreads();
    return r;
}

// K3: per-row logsumexp + gather + feat row norm -> rowlp/rownm
__global__ __launch_bounds__(256) void k_loss(
    const unsigned short* __restrict__ featb, const float* __restrict__ logits,
    const int* __restrict__ y, float* __restrict__ rowlp, float* __restrict__ rownm)
{
    __shared__ float sred[4];
    const int b = blockIdx.x, t = threadIdx.x;

    float s = 0.f;
#pragma unroll
    for (int c = 0; c < 2; ++c) {
        float v = bf2f(featb[b * ND + t * 2 + c]); s += v * v;
    }
    float fn2 = block_reduce(s, sred, 0);

    const float* lr = logits + (size_t)b * NP;
    float lv[8], mx = -INFINITY;
#pragma unroll
    for (int j = 0; j < 8; ++j) { lv[j] = lr[t + 256 * j]; mx = fmaxf(mx, lv[j]); }
    float MX = block_reduce(mx, sred, 1);
    float es = 0.f;
#pragma unroll
    for (int j = 0; j < 8; ++j) es += __expf(lv[j] - MX);
    float SUM = block_reduce(es, sred, 0);

    if (t == 0) {
        float ly = lr[y[b]];
        rowlp[b] = ly - MX - __logf(SUM);
        rownm[b] = sqrtf(fn2);
    }
}

// K4: final 256-wide reduction -> (loss, reg_e)
__global__ __launch_bounds__(256) void k_final(
    const float* __restrict__ rowlp, const float* __restrict__ rownm,
    float* __restrict__ tail)
{
    __shared__ float sred[4];
    const int t = threadIdx.x;
    float s1 = block_reduce(rowlp[t], sred, 0);
    float s2 = block_reduce(rownm[t], sred, 0);
    if (t == 0) {
        tail[0] = -s1 / (float)NB;
        tail[1] =  s2 / (float)NB;
    }
}

extern "C" void kernel_launch(void* const* d_in, const int* in_sizes, int n_in,
                              void* d_out, int out_size, void* d_ws, size_t ws_size,
                              hipStream_t stream)
{
    const float* x       = (const float*)d_in[0];
    const int*   y       = (const int*)  d_in[1];
    const float* Wb      = (const float*)d_in[2];
    const float* bb      = (const float*)d_in[3];
    const float* Wm      = (const float*)d_in[4];
    const float* bm      = (const float*)d_in[5];
    const float* proxies = (const float*)d_in[6];

    char* ws = (char*)d_ws;
    unsigned short* WPb    = (unsigned short*)(ws + OFF_WPB);
    unsigned short* featb  = (unsigned short*)(ws + OFF_FEATB);
    float*          pn2    = (float*)(ws + OFF_PN2);
    float*          logits = (float*)(ws + OFF_LOGITS);
    float*          rowlp  = (float*)(ws + OFF_ROWLP);
    float*          rownm  = (float*)(ws + OFF_ROWNM);

    float* out  = (float*)d_out;
    float* tail = out + (size_t)NB * NP;

    k_prep <<<dim3(NTOT / 4), dim3(256), 0, stream>>>(Wm, proxies, WPb, pn2);
    k_feat <<<dim3(ND / 64, NB / 64), dim3(256), 0, stream>>>(x, Wb, bb, featb);
    k_head <<<dim3(NTOT / 64, NB / 64), dim3(256), 0, stream>>>(
        featb, WPb, bm, pn2, out, logits);
    k_loss <<<dim3(NB), dim3(256), 0, stream>>>(featb, logits, y, rowlp, rownm);
    k_final<<<dim3(1), dim3(256), 0, stream>>>(rowlp, rownm, tail);
}

// Round 7
// 97.168 us; speedup vs baseline: 1.5590x; 1.1079x over previous
//
#include <hip/hip_runtime.h>
#include <hip/hip_bf16.h>
#include <math.h>

#define NB   256
#define KIN  1024
#define ND   512
#define NP   2048
#define NTOT 4096   // Wm rows + proxy rows stacked

typedef __bf16 bf16x8 __attribute__((ext_vector_type(8)));
typedef float  f32x4  __attribute__((ext_vector_type(4)));
typedef unsigned short ush8 __attribute__((ext_vector_type(8)));

// ws byte offsets (16B aligned)
#define OFF_WPB    0u          // 4096*512 bf16 = 4 MB
#define OFF_FEAT32 4194304u    // 256*512 f32   = 512 KB
#define OFF_PN2    4718592u    // 2048 f32
#define OFF_LOGITS 4726784u    // 256*2048 f32  = 2 MB
#define OFF_ROWLP  6823936u    // 256 f32
#define OFF_ROWNM  6824960u    // 256 f32

__device__ __forceinline__ ush8 pack8(float4 f0, float4 f1) {
    union { ush8 v; __hip_bfloat162 h[4]; } o;
    o.h[0] = __float22bfloat162_rn(make_float2(f0.x, f0.y));
    o.h[1] = __float22bfloat162_rn(make_float2(f0.z, f0.w));
    o.h[2] = __float22bfloat162_rn(make_float2(f1.x, f1.y));
    o.h[3] = __float22bfloat162_rn(make_float2(f1.z, f1.w));
    return o.v;
}
__device__ __forceinline__ float4 add4(float4 a, float4 b) {
    return make_float4(a.x + b.x, a.y + b.y, a.z + b.z, a.w + b.w);
}

// ---------------------------------------------------------------------------
// K0: cast Wm+prox -> WPb (bf16) + pn2 fused + zero feat32.
// 1024 blocks x 4 waves; wave w of block b owns row b*4+w.
// ---------------------------------------------------------------------------
__global__ __launch_bounds__(256) void k_prep(
    const float* __restrict__ Wm, const float* __restrict__ prox,
    unsigned short* __restrict__ WPb, float* __restrict__ pn2,
    float* __restrict__ feat32)
{
    const int t = threadIdx.x, lane = t & 63, w = t >> 6;
    if (t < 128) feat32[blockIdx.x * 128 + t] = 0.f;   // 1024*128 = 131072
    const int r = blockIdx.x * 4 + w;      // 0..4095
    const float* src = (r < NP) ? (Wm + (size_t)r * ND)
                                : (prox + (size_t)(r - NP) * ND);
    float4 v0 = *(const float4*)(src + lane * 8);
    float4 v1 = *(const float4*)(src + lane * 8 + 4);
    *(ush8*)(WPb + (size_t)r * ND + lane * 8) = pack8(v0, v1);
    if (r >= NP) {
        float s = v0.x*v0.x + v0.y*v0.y + v0.z*v0.z + v0.w*v0.w
                + v1.x*v1.x + v1.y*v1.y + v1.z*v1.z + v1.w*v1.w;
#pragma unroll
        for (int off = 32; off; off >>= 1) s += __shfl_down(s, off);
        if (lane == 0) pn2[r - NP] = s;
    }
}

// ---------------------------------------------------------------------------
// K1: feat GEMM split-K=8: feat32 += x @ Wb.T (no bias here).
// grid (8,4,8) = 256 blocks, 64x64 tile, K-chunk 128 = 4 steps of BK=32.
// ---------------------------------------------------------------------------
__global__ __launch_bounds__(256) void k_feat(
    const float* __restrict__ x, const float* __restrict__ Wb,
    float* __restrict__ feat32)
{
    __shared__ unsigned short As[2][64 * 32];
    __shared__ unsigned short Bs[2][64 * 32];
    const int t = threadIdx.x, lane = t & 63, w = t >> 6;
    const int n0 = blockIdx.x * 64, m0 = blockIdx.y * 64, k0 = blockIdx.z * 128;
    const int srow = t >> 2, sc = (t & 3) * 8;
    const float* gA = x  + (size_t)(m0 + srow) * KIN + k0 + sc;
    const float* gB = Wb + (size_t)(n0 + srow) * KIN + k0 + sc;
    float4 a0 = *(const float4*)gA, a1 = *(const float4*)(gA + 4);
    float4 b0 = *(const float4*)gB, b1 = *(const float4*)(gB + 4);
    f32x4 acc[2][2] = {};
    const int wm = (w >> 1) * 32, wn = (w & 1) * 32;
    const int arow = wm + (lane & 15), brow = wn + (lane & 15);
    const int fcol = (lane >> 4) * 8;
#pragma unroll
    for (int ks = 0; ks < 4; ++ks) {
        *(ush8*)&As[ks & 1][srow * 32 + sc] = pack8(a0, a1);
        *(ush8*)&Bs[ks & 1][srow * 32 + sc] = pack8(b0, b1);
        __syncthreads();
        if (ks + 1 < 4) {                  // prefetch flies under MFMAs
            a0 = *(const float4*)(gA + (ks + 1) * 32);
            a1 = *(const float4*)(gA + (ks + 1) * 32 + 4);
            b0 = *(const float4*)(gB + (ks + 1) * 32);
            b1 = *(const float4*)(gB + (ks + 1) * 32 + 4);
        }
        const unsigned short* as = &As[ks & 1][0];
        const unsigned short* bs = &Bs[ks & 1][0];
        bf16x8 af0 = *(const bf16x8*)&as[(arow     ) * 32 + fcol];
        bf16x8 af1 = *(const bf16x8*)&as[(arow + 16) * 32 + fcol];
        bf16x8 bf0 = *(const bf16x8*)&bs[(brow     ) * 32 + fcol];
        bf16x8 bf1 = *(const bf16x8*)&bs[(brow + 16) * 32 + fcol];
        acc[0][0] = __builtin_amdgcn_mfma_f32_16x16x32_bf16(af0, bf0, acc[0][0], 0, 0, 0);
        acc[0][1] = __builtin_amdgcn_mfma_f32_16x16x32_bf16(af0, bf1, acc[0][1], 0, 0, 0);
        acc[1][0] = __builtin_amdgcn_mfma_f32_16x16x32_bf16(af1, bf0, acc[1][0], 0, 0, 0);
        acc[1][1] = __builtin_amdgcn_mfma_f32_16x16x32_bf16(af1, bf1, acc[1][1], 0, 0, 0);
    }
    const int q = lane >> 4, cn = lane & 15;
#pragma unroll
    for (int i = 0; i < 2; ++i)
#pragma unroll
        for (int j = 0; j < 2; ++j) {
            const int n = n0 + wn + 16 * j + cn;
#pragma unroll
            for (int r = 0; r < 4; ++r) {
                const int m = m0 + wm + 16 * i + q * 4 + r;
                atomicAdd(&feat32[m * ND + n], acc[i][j][r]);
            }
        }
}

// ---------------------------------------------------------------------------
// K2: head GEMM, 64x64 tile x 256 blocks. A staged from fp32 feat32 + bb
// with inline bf16 cvt; B from bf16 WPb. dbuf + register prefetch.
//  n<2048: out = feat@Wm.T + bm ; n>=2048: logits = 2*feat@prox.T - pn2
// ---------------------------------------------------------------------------
__global__ __launch_bounds__(256) void k_head(
    const float* __restrict__ feat32, const float* __restrict__ bb,
    const unsigned short* __restrict__ WPb,
    const float* __restrict__ bm, const float* __restrict__ pn2,
    float* __restrict__ out, float* __restrict__ logits)
{
    __shared__ unsigned short As[2][64 * 32];
    __shared__ unsigned short Bs[2][64 * 32];
    const int t = threadIdx.x, lane = t & 63, w = t >> 6;
    const int n0 = blockIdx.x * 64;   // 64 n-tiles over 4096
    const int m0 = blockIdx.y * 64;   // 4 m-tiles over 256
    const int srow = t >> 2, sc = (t & 3) * 8;
    const float*          gA = feat32 + (size_t)(m0 + srow) * ND + sc;
    const unsigned short* gB = WPb    + (size_t)(n0 + srow) * ND + sc;
    float4 a0 = *(const float4*)gA, a1 = *(const float4*)(gA + 4);
    float4 u0 = *(const float4*)(bb + sc), u1 = *(const float4*)(bb + sc + 4);
    ush8 vb = *(const ush8*)gB;
    f32x4 acc[2][2] = {};
    const int wm = (w >> 1) * 32, wn = (w & 1) * 32;
    const int fr = lane & 15, fcol = (lane >> 4) * 8;
    for (int ks = 0; ks < ND / 32; ++ks) {
        *(ush8*)&As[ks & 1][srow * 32 + sc] = pack8(add4(a0, u0), add4(a1, u1));
        *(ush8*)&Bs[ks & 1][srow * 32 + sc] = vb;
        __syncthreads();
        if (ks + 1 < ND / 32) {
            a0 = *(const float4*)(gA + (ks + 1) * 32);
            a1 = *(const float4*)(gA + (ks + 1) * 32 + 4);
            u0 = *(const float4*)(bb + (ks + 1) * 32 + sc);
            u1 = *(const float4*)(bb + (ks + 1) * 32 + sc + 4);
            vb = *(const ush8*)(gB + (ks + 1) * 32);
        }
        const unsigned short* as = &As[ks & 1][0];
        const unsigned short* bs = &Bs[ks & 1][0];
        bf16x8 af0 = *(const bf16x8*)&as[(wm      + fr) * 32 + fcol];
        bf16x8 af1 = *(const bf16x8*)&as[(wm + 16 + fr) * 32 + fcol];
        bf16x8 bf0 = *(const bf16x8*)&bs[(wn      + fr) * 32 + fcol];
        bf16x8 bf1 = *(const bf16x8*)&bs[(wn + 16 + fr) * 32 + fcol];
        acc[0][0] = __builtin_amdgcn_mfma_f32_16x16x32_bf16(af0, bf0, acc[0][0], 0, 0, 0);
        acc[0][1] = __builtin_amdgcn_mfma_f32_16x16x32_bf16(af0, bf1, acc[0][1], 0, 0, 0);
        acc[1][0] = __builtin_amdgcn_mfma_f32_16x16x32_bf16(af1, bf0, acc[1][0], 0, 0, 0);
        acc[1][1] = __builtin_amdgcn_mfma_f32_16x16x32_bf16(af1, bf1, acc[1][1], 0, 0, 0);
    }
    const bool isProxy = (n0 >= NP);
    const int q = lane >> 4;
#pragma unroll
    for (int i = 0; i < 2; ++i)
#pragma unroll
        for (int j = 0; j < 2; ++j) {
            const int n = n0 + wn + 16 * j + fr;
            const float cadd = isProxy ? pn2[n - NP] : bm[n];
#pragma unroll
            for (int r = 0; r < 4; ++r) {
                const int m = m0 + wm + 16 * i + q * 4 + r;
                const float v = acc[i][j][r];
                if (isProxy) logits[m * NP + (n - NP)] = 2.0f * v - cadd;
                else         out[m * NP + n] = v + cadd;
            }
        }
}

__device__ __forceinline__ float block_reduce(float v, float* sred, int op)
{
    const int lane = threadIdx.x & 63, wave = threadIdx.x >> 6;
#pragma unroll
    for (int off = 32; off; off >>= 1) {
        float o = __shfl_down(v, off);
        v = op ? fmaxf(v, o) : (v + o);
    }
    if (lane == 0) sred[wave] = v;
    __syncthreads();
    if (threadIdx.x == 0) {
        float r = sred[0];
#pragma unroll
        for (int wv = 1; wv < 4; ++wv) r = op ? fmaxf(r, sred[wv]) : (r + sred[wv]);
        sred[0] = r;
    }
    __syncthreads();
    float r = sred[0];
    __syncthreads();
    return r;
}

// K3: per-row logsumexp + gather + feat row norm (fp32 feat + bias)
__global__ __launch_bounds__(256) void k_loss(
    const float* __restrict__ feat32, const float* __restrict__ bb,
    const float* __restrict__ logits, const int* __restrict__ y,
    float* __restrict__ rowlp, float* __restrict__ rownm)
{
    __shared__ float sred[4];
    const int b = blockIdx.x, t = threadIdx.x;

    float v0 = feat32[b * ND + t] + bb[t];
    float v1 = feat32[b * ND + t + 256] + bb[t + 256];
    float fn2 = block_reduce(v0 * v0 + v1 * v1, sred, 0);

    const float* lr = logits + (size_t)b * NP;
    float lv[8], mx = -INFINITY;
#pragma unroll
    for (int j = 0; j < 8; ++j) { lv[j] = lr[t + 256 * j]; mx = fmaxf(mx, lv[j]); }
    float MX = block_reduce(mx, sred, 1);
    float es = 0.f;
#pragma unroll
    for (int j = 0; j < 8; ++j) es += __expf(lv[j] - MX);
    float SUM = block_reduce(es, sred, 0);

    if (t == 0) {
        float ly = lr[y[b]];
        rowlp[b] = ly - MX - __logf(SUM);
        rownm[b] = sqrtf(fn2);
    }
}

// K4: final 256-wide reduction -> (loss, reg_e)
__global__ __launch_bounds__(256) void k_final(
    const float* __restrict__ rowlp, const float* __restrict__ rownm,
    float* __restrict__ tail)
{
    __shared__ float sred[4];
    const int t = threadIdx.x;
    float s1 = block_reduce(rowlp[t], sred, 0);
    float s2 = block_reduce(rownm[t], sred, 0);
    if (t == 0) {
        tail[0] = -s1 / (float)NB;
        tail[1] =  s2 / (float)NB;
    }
}

extern "C" void kernel_launch(void* const* d_in, const int* in_sizes, int n_in,
                              void* d_out, int out_size, void* d_ws, size_t ws_size,
                              hipStream_t stream)
{
    const float* x       = (const float*)d_in[0];
    const int*   y       = (const int*)  d_in[1];
    const float* Wb      = (const float*)d_in[2];
    const float* bb      = (const float*)d_in[3];
    const float* Wm      = (const float*)d_in[4];
    const float* bm      = (const float*)d_in[5];
    const float* proxies = (const float*)d_in[6];

    char* ws = (char*)d_ws;
    unsigned short* WPb    = (unsigned short*)(ws + OFF_WPB);
    float*          feat32 = (float*)(ws + OFF_FEAT32);
    float*          pn2    = (float*)(ws + OFF_PN2);
    float*          logits = (float*)(ws + OFF_LOGITS);
    float*          rowlp  = (float*)(ws + OFF_ROWLP);
    float*          rownm  = (float*)(ws + OFF_ROWNM);

    float* out  = (float*)d_out;
    float* tail = out + (size_t)NB * NP;

    k_prep <<<dim3(NTOT / 4), dim3(256), 0, stream>>>(Wm, proxies, WPb, pn2, feat32);
    k_feat <<<dim3(ND / 64, NB / 64, 8), dim3(256), 0, stream>>>(x, Wb, feat32);
    k_head <<<dim3(NTOT / 64, NB / 64), dim3(256), 0, stream>>>(
        feat32, bb, WPb, bm, pn2, out, logits);
    k_loss <<<dim3(NB), dim3(256), 0, stream>>>(feat32, bb, logits, y, rowlp, rownm);
    k_final<<<dim3(1), dim3(256), 0, stream>>>(rowlp, rownm, tail);
}